// Round 3
// baseline (284.169 us; speedup 1.0000x reference)
//
#include <hip/hip_runtime.h>
#include <hip/hip_bf16.h>

typedef __attribute__((ext_vector_type(8)))  short          bf16x8;
typedef __attribute__((ext_vector_type(8)))  unsigned short us8;
typedef __attribute__((ext_vector_type(4)))  unsigned short us4;
typedef __attribute__((ext_vector_type(16))) float          f32x16;

// round-to-nearest-even f32 -> bf16 (bit trick; inputs are finite)
static __device__ __forceinline__ unsigned short f2bf(float f) {
    union { float f; unsigned int u; } v; v.f = f;
    unsigned int u = v.u;
    unsigned int r = u + 0x7fffu + ((u >> 16) & 1u);
    return (unsigned short)(r >> 16);
}

static __device__ __forceinline__ bf16x8 pack8(float4 a, float4 b) {
    bf16x8 r;
    r[0] = (short)f2bf(a.x); r[1] = (short)f2bf(a.y);
    r[2] = (short)f2bf(a.z); r[3] = (short)f2bf(a.w);
    r[4] = (short)f2bf(b.x); r[5] = (short)f2bf(b.y);
    r[6] = (short)f2bf(b.z); r[7] = (short)f2bf(b.w);
    return r;
}

// block 0: W1 f32 -> bf16 (20480 elems). blocks 1..: x f32 -> bf16 (if do_x)
__global__ __launch_bounds__(256) void prep_kernel(
    const float* __restrict__ W1, const float* __restrict__ x,
    unsigned short* __restrict__ w1b, unsigned short* __restrict__ xb,
    int nx, int do_x)
{
    if (blockIdx.x == 0) {
        for (int i = threadIdx.x; i < 128 * 160; i += 256)
            w1b[i] = f2bf(W1[i]);
    } else if (do_x) {
        int n4 = nx >> 2;
        int idx = (blockIdx.x - 1) * 256 + threadIdx.x;
        int stride = (gridDim.x - 1) * 256;
        for (int i = idx; i < n4; i += stride) {
            float4 f = ((const float4*)x)[i];
            us4 o = { f2bf(f.x), f2bf(f.y), f2bf(f.z), f2bf(f.w) };
            ((us4*)xb)[i] = o;
        }
    }
}

// Fused: gather -> L1 (bf16 MFMA, fp32 acc) -> leaky -> L2 dot (fp32) -> leaky
// 256 threads = 4 waves; 128 edges/block; wave handles 32 edges x 128 hidden.
template <bool XB>
__global__ __launch_bounds__(256) void edge_mlp(
    const float* __restrict__ x, const unsigned short* __restrict__ xb,
    const int* __restrict__ ei, const float* __restrict__ ef,
    const unsigned short* __restrict__ w1b,
    const float* __restrict__ b1, const float* __restrict__ w2,
    const float* __restrict__ b2, float* __restrict__ out, int E)
{
    __shared__ unsigned short W1s[128][168];  // [hidden][k], pad 160->168
    __shared__ float b1s[128];
    __shared__ float w2s[128];

    const int t = threadIdx.x;
    // ---- stage W1 (bf16, 40KB, L2-resident source) ----
    {
        int j = t >> 1, h = t & 1;
        const unsigned short* src = w1b + j * 160 + h * 80;
        unsigned short* dst = &W1s[j][h * 80];
        #pragma unroll
        for (int i = 0; i < 10; i++)
            *(us8*)(dst + i * 8) = *(const us8*)(src + i * 8);
    }
    if (t < 128) { b1s[t] = b1[t]; w2s[t] = w2[t]; }
    __syncthreads();

    const int lane = t & 63;
    const int wv   = t >> 6;
    const int m    = lane & 31;   // A row within wave's m-tile / B col
    const int kg   = lane >> 5;   // k-group (0/1): k = ks*16 + kg*8 + j
    const float b2v = b2[0];

    long e = (long)blockIdx.x * 128 + wv * 32 + m;
    int eidx = (int)((e < (long)E) ? e : (long)(E - 1));  // clamp tail
    int o = ei[eidx];
    int d = ei[(size_t)E + eidx];

    // ---- A fragments: 10 k-steps x 8 bf16, straight from global ----
    bf16x8 afrag[10];
    if constexpr (XB) {
        const bf16x8* xo = (const bf16x8*)(xb + (size_t)o * 64 + kg * 8);
        const bf16x8* xd = (const bf16x8*)(xb + (size_t)d * 64 + kg * 8);
        #pragma unroll
        for (int ks = 0; ks < 4; ks++) afrag[ks]     = xo[ks * 2];
        #pragma unroll
        for (int ks = 0; ks < 4; ks++) afrag[4 + ks] = xd[ks * 2];
    } else {
        const float4* xo = (const float4*)(x + (size_t)o * 64 + kg * 8);
        const float4* xd = (const float4*)(x + (size_t)d * 64 + kg * 8);
        #pragma unroll
        for (int ks = 0; ks < 4; ks++) afrag[ks]     = pack8(xo[ks * 4], xo[ks * 4 + 1]);
        #pragma unroll
        for (int ks = 0; ks < 4; ks++) afrag[4 + ks] = pack8(xd[ks * 4], xd[ks * 4 + 1]);
    }
    {
        const float4* pef = (const float4*)(ef + (size_t)eidx * 32 + kg * 8);
        #pragma unroll
        for (int ks = 0; ks < 2; ks++)
            afrag[8 + ks] = pack8(pef[ks * 4], pef[ks * 4 + 1]);
    }

    // ---- layer 1: 40 x mfma_f32_32x32x16_bf16 ----
    f32x16 acc[4];
    #pragma unroll
    for (int i = 0; i < 4; i++)
        #pragma unroll
        for (int r = 0; r < 16; r++) acc[i][r] = 0.0f;

    #pragma unroll
    for (int ks = 0; ks < 10; ks++) {
        const int kb = ks * 16 + kg * 8;
        #pragma unroll
        for (int nt = 0; nt < 4; nt++) {
            bf16x8 bfr = *(const bf16x8*)&W1s[nt * 32 + m][kb];
            acc[nt] = __builtin_amdgcn_mfma_f32_32x32x16_bf16(afrag[ks], bfr, acc[nt], 0, 0, 0);
        }
    }

    // ---- layer 2 (fp32): per-lane partial over 4 n-tiles ----
    const int c = m;  // C/D col = lane&31
    float b1v[4], w2v[4];
    #pragma unroll
    for (int nt = 0; nt < 4; nt++) {
        b1v[nt] = b1s[nt * 32 + c];
        w2v[nt] = w2s[nt * 32 + c];
    }
    float s[16];
    #pragma unroll
    for (int r = 0; r < 16; r++) {
        float a = 0.0f;
        #pragma unroll
        for (int nt = 0; nt < 4; nt++) {
            float h = acc[nt][r] + b1v[nt];
            h = fmaxf(h, 0.01f * h);  // leaky relu (slope<1)
            a = fmaf(h, w2v[nt], a);
        }
        s[r] = a;
    }

    // ---- hierarchical butterfly: 16 values over 32 cols in 16 shuffles ----
    // after step k, lane c owns regs with bit_k == c bit_k
    #pragma unroll
    for (int k = 0; k < 4; k++) {
        const int msk = 1 << k;
        const int bit = (c >> k) & 1;
        #pragma unroll
        for (int j = 0; j < (8 >> k); j++) {
            float a0 = s[2 * j], a1 = s[2 * j + 1];
            float keep = bit ? a1 : a0;
            float send = bit ? a0 : a1;
            s[j] = keep + __shfl_xor(send, msk, 64);
        }
    }
    float tot = s[0] + __shfl_xor(s[0], 16, 64);  // other 16 cols

    if ((c & 16) == 0) {
        // lane owns C/D row = (reg&3) + 8*(reg>>2) + 4*hi, reg = c&15, hi = kg
        int row = (c & 3) + 4 * kg + 8 * ((c >> 2) & 3);
        long oidx = (long)blockIdx.x * 128 + wv * 32 + row;
        if (oidx < (long)E) {
            float v = tot + b2v;
            out[oidx] = fmaxf(v, 0.01f * v);
        }
    }
}

extern "C" void kernel_launch(void* const* d_in, const int* in_sizes, int n_in,
                              void* d_out, int out_size, void* d_ws, size_t ws_size,
                              hipStream_t stream)
{
    const float* x  = (const float*)d_in[0];
    const int*   ei = (const int*)d_in[1];
    const float* ef = (const float*)d_in[2];
    const float* W1 = (const float*)d_in[3];
    const float* b1 = (const float*)d_in[4];
    const float* w2 = (const float*)d_in[5];
    const float* b2 = (const float*)d_in[6];
    float* out = (float*)d_out;

    const int E  = in_sizes[1] / 2;
    const int nx = in_sizes[0];

    unsigned short* w1b = (unsigned short*)d_ws;
    unsigned short* xb  = (unsigned short*)((char*)d_ws + 65536);
    const bool use_xb = ws_size >= (size_t)65536 + (size_t)nx * 2;

    const int nblk = (E + 127) / 128;
    prep_kernel<<<use_xb ? 2048 : 1, 256, 0, stream>>>(W1, x, w1b, xb, nx, use_xb ? 1 : 0);
    if (use_xb)
        edge_mlp<true><<<nblk, 256, 0, stream>>>(x, xb, ei, ef, w1b, b1, w2, b2, out, E);
    else
        edge_mlp<false><<<nblk, 256, 0, stream>>>(x, xb, ei, ef, w1b, b1, w2, b2, out, E);
}